// Round 17
// baseline (108.631 us; speedup 1.0000x reference)
//
#include <hip/hip_runtime.h>
#include <hip/hip_bf16.h>

#define BATCH 16
#define INP   128
#define OUP   128
#define HH    56
#define WW    56
#define HWSZ  3136
#define HID   768
#define EPSV  1e-5f

#define CPST  521             // k23 stg per-cp stride (dw): 512 DMA'd + 9 pad; odd -> banks clean
#define H2STR 66              // h2s ushort stride (33 dw, odd)
#define XSTR  130             // k1 xs ushort stride (65 dw, odd)
#define H1ROW 64              // h1 padded row (dw): px c at dword 4+c
#define H1RPC 58              // rows per channel-pair plane: guard + 56 + guard

typedef __attribute__((ext_vector_type(8))) short bf16x8;
typedef __attribute__((ext_vector_type(4))) float f32x4;
typedef __attribute__((ext_vector_type(2))) float f32x2;
typedef __attribute__((address_space(1))) const unsigned GU;
typedef __attribute__((address_space(3))) unsigned LU;

__device__ __forceinline__ unsigned short f2b(float f) {
    unsigned u = __float_as_uint(f);
    return (unsigned short)((u + 0x7FFFu + ((u >> 16) & 1u)) >> 16);   // RNE
}
__device__ __forceinline__ float blo(unsigned u){ return __uint_as_float(u << 16); }
__device__ __forceinline__ float bhi(unsigned u){ return __uint_as_float(u & 0xFFFF0000u); }
__device__ __forceinline__ unsigned pkbf(float lo, float hi) {
    unsigned r;
    asm("v_cvt_pk_bf16_f32 %0, %1, %2" : "=v"(r) : "v"(lo), "v"(hi));
    return r;
}
__device__ __forceinline__ void pkfma(f32x2& a, f32x2 b, f32x2 c) {   // a = b*c + a
    asm("v_pk_fma_f32 %0, %1, %2, %0" : "+v"(a) : "v"(b), "v"(c));
}

// ---------------- prep: fold BN into bf16 weights + mask dilate + cheap h1 pad zeroing ----------------
__global__ void prep(const float* __restrict__ w1, const float* __restrict__ g1,
                     const float* __restrict__ b1, const float* __restrict__ m1, const float* __restrict__ v1,
                     const float* __restrict__ wdw, const float* __restrict__ g2,
                     const float* __restrict__ b2, const float* __restrict__ m2, const float* __restrict__ v2,
                     const float* __restrict__ w2, const float* __restrict__ g3,
                     const float* __restrict__ b3, const float* __restrict__ m3, const float* __restrict__ v3,
                     const int* __restrict__ mask,
                     unsigned short* __restrict__ w1f, unsigned short* __restrict__ w2f,
                     float* __restrict__ be1o, float* __restrict__ wdsf,
                     float* __restrict__ be2o, float* __restrict__ be3o,
                     float* __restrict__ mdf, float* __restrict__ mff,
                     unsigned* __restrict__ h1p)
{
    int gid = blockIdx.x * blockDim.x + threadIdx.x;
    int stp = gridDim.x * blockDim.x;
    // w1 fragment-linear: [ht 48][ks 4][g 4][r16 16][e 8]
    for (int i = gid; i < HID * INP; i += stp) {
        int r = i >> 7, k = i & 127;
        float s = g1[r] * rsqrtf(v1[r] + EPSV);
        int ht = r >> 4, r16 = r & 15, ks = k >> 5, g = (k >> 3) & 3, e = k & 7;
        w1f[((((ht * 4 + ks) * 4 + g) * 16 + r16) << 3) + e] = f2b(w1[i] * s);
    }
    // w2 fragment-linear: [ot 8][ch 12][ks 2][lane 64][e 8]
    for (int i = gid; i < OUP * HID; i += stp) {
        int r = i / HID, k = i - r * HID;
        float s = g3[r] * rsqrtf(v3[r] + EPSV);
        int ot = r >> 4, r16 = r & 15, ch = k >> 6, ks = (k >> 5) & 1, g = (k >> 3) & 3, e = k & 7;
        int lane = g * 16 + r16;
        w2f[((((ot * 12 + ch) * 2 + ks) * 64 + lane) << 3) + e] = f2b(w2[i] * s);
    }
    for (int i = gid; i < HID; i += stp) {
        float s1 = g1[i] * rsqrtf(v1[i] + EPSV);
        be1o[i] = b1[i] - m1[i] * s1;
        float s2 = g2[i] * rsqrtf(v2[i] + EPSV);
        be2o[i] = b2[i] - m2[i] * s2;
    }
    for (int i = gid; i < HID * 9; i += stp) {          // tap-major [q][c], BN2 scale folded
        int q = i / HID, c = i - q * HID;
        float s2 = g2[c] * rsqrtf(v2[c] + EPSV);
        wdsf[i] = wdw[c * 9 + q] * s2;
    }
    for (int i = gid; i < OUP; i += stp) {
        float s3 = g3[i] * rsqrtf(v3[i] + EPSV);
        be3o[i] = b3[i] - m3[i] * s3;
    }
    for (int i = gid; i < BATCH * HWSZ; i += stp) {     // mf + 3x3 dilated md
        int b = i / HWSZ, p = i - b * HWSZ;
        int y = p / WW, xx = p - y * WW;
        float mf = (float)mask[i];
        float md = 0.f;
        for (int dy = -1; dy <= 1; ++dy)
            for (int dx = -1; dx <= 1; ++dx) {
                int yy = y + dy, xc = xx + dx;
                if (yy >= 0 && yy < HH && xc >= 0 && xc < WW)
                    md = fmaxf(md, (float)mask[b * HWSZ + yy * WW + xc]);
            }
        mff[i] = mf;
        mdf[i] = md;
    }
    // h1 guard rows (idx 0 and 57), uint4 stores
    uint4 z4; z4.x = 0; z4.y = 0; z4.z = 0; z4.w = 0;
    for (int i = gid; i < BATCH * 384 * 2 * 16; i += stp) {
        int rr = i >> 4, q4 = i & 15;
        int bcp = rr >> 1, side = rr & 1;
        *(uint4*)&h1p[((size_t)bcp * H1RPC + (side ? 57 : 0)) * H1ROW + q4 * 4] = z4;
    }
    // col pads of data rows: only dwords 3 (px=-1) and 60 (px=56) are ever read
    for (int i = gid; i < BATCH * 384 * 56; i += stp) {
        int bcp = i / 56, row = i - bcp * 56;
        size_t base = ((size_t)bcp * H1RPC + 1 + row) * H1ROW;
        h1p[base + 3] = 0;
        h1p[base + 60] = 0;
    }
}

// ---------------- K1: expand GEMM -> h1 (bf16 pairs, padded rows) — r16 ----------------
__launch_bounds__(512, 4)
__global__ void k1_expand(const float* __restrict__ x,
                          const unsigned short* __restrict__ w1f,
                          const float* __restrict__ be1g,
                          const float* __restrict__ mdf,
                          unsigned* __restrict__ h1p)
{
    __shared__ unsigned short xs[128 * XSTR];   // 33.3 KB bf16 x-tile [px][c], odd dw stride
    const int t = threadIdx.x, lane = t & 63, wv = t >> 6;
    const int g = lane >> 4, r16 = lane & 15;
    const int pid = blockIdx.x;
    const int l = (pid & 7) * 150 + (pid >> 3);
    const int hb = l % 3;
    const int pb = (l / 3) % 25;
    const int b  = l / 75;
    const int p0 = pb * 128;
    const int whid = wv & 3;
    const int wpx  = wv >> 2;

    for (int rep = 0; rep < 8; ++rep) {
        int id = t + rep * 512;
        int px = id & 127, c4 = id >> 7;
        int p = p0 + px;
        ushort4 u; u.x = 0; u.y = 0; u.z = 0; u.w = 0;
        if (p < HWSZ) {
            const float* xp = x + ((size_t)(b * INP + c4 * 4)) * HWSZ + p;
            unsigned lo = pkbf(xp[0], xp[HWSZ]);
            unsigned hi = pkbf(xp[2 * HWSZ], xp[3 * HWSZ]);
            u.x = (unsigned short)lo; u.y = (unsigned short)(lo >> 16);
            u.z = (unsigned short)hi; u.w = (unsigned short)(hi >> 16);
        }
        *(ushort4*)&xs[px * XSTR + (((c4 >> 1) ^ (px & 15)) << 3) + ((c4 & 1) << 2)] = u;
    }
    __syncthreads();

    f32x4 acc[4][4];
    #pragma unroll
    for (int mt = 0; mt < 4; ++mt)
        #pragma unroll
        for (int nt = 0; nt < 4; ++nt) {
            acc[mt][nt][0] = 0.f; acc[mt][nt][1] = 0.f;
            acc[mt][nt][2] = 0.f; acc[mt][nt][3] = 0.f;
        }
    const int hbase = hb * 256 + whid * 64;
    const int htb = hbase >> 4;

    #pragma unroll
    for (int ks = 0; ks < 4; ++ks) {
        bf16x8 af[4];
        #pragma unroll
        for (int mt = 0; mt < 4; ++mt)
            af[mt] = *(const bf16x8*)&w1f[((((htb + mt) * 4 + ks) * 64) + lane) << 3];
        #pragma unroll
        for (int nt = 0; nt < 4; ++nt) {
            int px = wpx * 64 + nt * 16 + r16;
            bf16x8 bf = *(const bf16x8*)&xs[px * XSTR + (((ks * 4 + g) ^ r16) << 3)];
            #pragma unroll
            for (int mt = 0; mt < 4; ++mt)
                acc[mt][nt] = __builtin_amdgcn_mfma_f32_16x16x32_bf16(af[mt], bf, acc[mt][nt], 0, 0, 0);
        }
    }

    #pragma unroll
    for (int nt = 0; nt < 4; ++nt) {
        const int pg = p0 + wpx * 64 + nt * 16;
        if (pg >= HWSZ) continue;
        const int p = pg + r16;
        const int row = (p * 9363) >> 19;           // p/56
        const int col = p - row * 56;
        const float md = mdf[b * HWSZ + p];
        #pragma unroll
        for (int mt = 0; mt < 4; ++mt) {
            const float4 be4 = *(const float4*)&be1g[hbase + mt * 16 + g * 4];
            f32x4 a = acc[mt][nt];
            float v0 = fminf(fmaxf(a[0] + be4.x, 0.f), 6.f) * md;
            float v1 = fminf(fmaxf(a[1] + be4.y, 0.f), 6.f) * md;
            float v2 = fminf(fmaxf(a[2] + be4.z, 0.f), 6.f) * md;
            float v3 = fminf(fmaxf(a[3] + be4.w, 0.f), 6.f) * md;
            const int c2 = (hbase >> 1) + mt * 8 + g * 2;
            const size_t ad = ((size_t)(b * 384 + c2) * H1RPC + row + 1) * H1ROW + 4 + col;
            h1p[ad] = pkbf(v0, v1);
            h1p[ad + H1RPC * H1ROW] = pkbf(v2, v3);
        }
    }
}

// ---------------- K23: 4-row strips, 224 blocks, DMA-staged, w2f reg-prefetch ----------------
__launch_bounds__(512, 2)
__global__ void k23(const unsigned* __restrict__ h1p,
                    const unsigned short* __restrict__ w2f,
                    const float* __restrict__ wdsf,
                    const float* __restrict__ be2g,
                    const float* __restrict__ be3g,
                    const float* __restrict__ mff,
                    const float* __restrict__ x,
                    float* __restrict__ out)
{
    __shared__ unsigned stg[32 * CPST];          // 66688 B  h1 [cp 32][8 rows x 64 dw + 9 pad]
    __shared__ unsigned short h2s[224 * H2STR];  // 29568 B  h2 [px][c], stride 66
    __shared__ float mfv_[224];                  //   896 B
    // total 97152 B -> 1 block/CU

    const int t = threadIdx.x, lane = t & 63, wv = t >> 6;
    const int g = lane >> 4, r16 = lane & 15;
    const int pid = blockIdx.x;
    const int l = (pid & 7) * 28 + (pid >> 3);   // XCD swizzle (224 = 8*28)
    const int strip = l % 14, b = l / 14;
    const int y0 = strip * 4, p0 = y0 * 56;      // 224 contiguous output px
    const int start = (y0 == 52) ? 50 : y0;      // DMA 8-row window start (plane idx)
    const int shift = y0 - start;                // 0 or 2

    if (t < 224) mfv_[t] = mff[b * HWSZ + p0 + t];

    // DMA: wave wv stages cp = wv*4..wv*4+3; 2 instrs per cp (8 rows = 2048 B)
    const unsigned* gb[4];
    unsigned* lb[4];
    #pragma unroll
    for (int i = 0; i < 4; ++i) {
        const int cpw = wv * 4 + i;
        gb[i] = h1p + (((size_t)(b * 384 + cpw) * H1RPC + start) << 6) + lane * 4;
        lb[i] = &stg[cpw * CPST];
    }
    auto dma = [&](int ch) {
        const size_t co = (size_t)ch * 32 * H1RPC * H1ROW;
        #pragma unroll
        for (int i = 0; i < 4; ++i) {
            __builtin_amdgcn_global_load_lds((GU*)(gb[i] + co), (LU*)lb[i], 16, 0, 0);
            __builtin_amdgcn_global_load_lds((GU*)(gb[i] + co + 256), (LU*)(lb[i] + 256), 16, 0, 0);
        }
    };

    // DW mapping: thread -> (cp 32, r4 4, q 4): 1 row, 14 px, 2 paired channels
    const int cp_c = t & 31;
    const int rq = t >> 5, r4 = rq & 3, q = rq >> 2;
    unsigned* const h2d = (unsigned*)h2s;
    bf16x8 pwreg[16];                            // w2f fragments for current chunk (prefetched)

    auto loadPW = [&](int ch) {
        #pragma unroll
        for (int ot = 0; ot < 8; ++ot)
            #pragma unroll
            for (int ks = 0; ks < 2; ++ks)
                pwreg[ot * 2 + ks] = *(const bf16x8*)&w2f[((((ot * 12 + ch) * 2 + ks) * 64) + lane) << 3];
    };

    auto phaseDW = [&](int ch) {
        f32x2 acc2[14];
        {
            const float2 be2 = *(const float2*)&be2g[ch * 64 + 2 * cp_c];
            #pragma unroll
            for (int j = 0; j < 14; ++j) { acc2[j][0] = be2.x; acc2[j][1] = be2.y; }
        }
        #pragma unroll
        for (int dy = 0; dy < 3; ++dy) {
            f32x2 wt0 = *(const f32x2*)&wdsf[(dy * 3 + 0) * HID + ch * 64 + 2 * cp_c];
            f32x2 wt1 = *(const f32x2*)&wdsf[(dy * 3 + 1) * HID + ch * 64 + 2 * cp_c];
            f32x2 wt2 = *(const f32x2*)&wdsf[(dy * 3 + 2) * HID + ch * 64 + 2 * cp_c];
            const unsigned* rp = &stg[cp_c * CPST + (r4 + shift + dy) * H1ROW + 4 + q * 14];
            f32x2 p[16];
            {
                unsigned u = rp[-1]; p[0][0] = blo(u); p[0][1] = bhi(u);
            }
            #pragma unroll
            for (int i = 0; i < 7; ++i) {         // b64 pairs (rp even-aligned)
                uint2 d = *(const uint2*)(rp + 2 * i);
                p[1 + 2 * i][0] = blo(d.x); p[1 + 2 * i][1] = bhi(d.x);
                p[2 + 2 * i][0] = blo(d.y); p[2 + 2 * i][1] = bhi(d.y);
            }
            {
                unsigned u = rp[14]; p[15][0] = blo(u); p[15][1] = bhi(u);
            }
            #pragma unroll
            for (int j = 0; j < 14; ++j) {
                pkfma(acc2[j], p[j], wt0);
                pkfma(acc2[j], p[j + 1], wt1);
                pkfma(acc2[j], p[j + 2], wt2);
            }
        }
        #pragma unroll
        for (int j = 0; j < 14; ++j) {
            const int px = r4 * 56 + q * 14 + j;
            const float mv = mfv_[px];
            float vL = __builtin_amdgcn_fmed3f(acc2[j][0], 0.f, 6.f) * mv;
            float vH = __builtin_amdgcn_fmed3f(acc2[j][1], 0.f, 6.f) * mv;
            h2d[px * 33 + cp_c] = pkbf(vL, vH);   // banks px*33+cp: clean
        }
    };

    // P: wave w -> px tiles {2w, 2w+1} (w<6) or {12+(w-6)} ; all 8 out-ch tiles
    const int t0 = (wv < 6) ? 2 * wv : 12 + (wv - 6);
    const bool has2 = wv < 6;
    f32x4 pacc[2][8];
    #pragma unroll
    for (int ti = 0; ti < 2; ++ti)
        #pragma unroll
        for (int ot = 0; ot < 8; ++ot) {
            pacc[ti][ot][0] = 0.f; pacc[ti][ot][1] = 0.f;
            pacc[ti][ot][2] = 0.f; pacc[ti][ot][3] = 0.f;
        }

    auto phaseP = [&]() {
        #pragma unroll
        for (int ks = 0; ks < 2; ++ks) {
            {
                const int px = t0 * 16 + r16;
                const bf16x8 hb = *(const bf16x8*)&h2s[px * H2STR + (ks * 4 + g) * 8];
                #pragma unroll
                for (int ot = 0; ot < 8; ++ot)
                    pacc[0][ot] = __builtin_amdgcn_mfma_f32_16x16x32_bf16(pwreg[ot * 2 + ks], hb, pacc[0][ot], 0, 0, 0);
            }
            if (has2) {
                const int px = (2 * wv + 1) * 16 + r16;
                const bf16x8 hb = *(const bf16x8*)&h2s[px * H2STR + (ks * 4 + g) * 8];
                #pragma unroll
                for (int ot = 0; ot < 8; ++ot)
                    pacc[1][ot] = __builtin_amdgcn_mfma_f32_16x16x32_bf16(pwreg[ot * 2 + ks], hb, pacc[1][ot], 0, 0, 0);
            }
        }
    };

    // ---- main loop: [loadPW(ch) + DW(ch)] bar [dma(ch+1) + P(ch)] bar ----
    dma(0);
    __syncthreads();                              // DMA landed (vmcnt drained at barrier)
    for (int ch = 0; ch < 12; ++ch) {
        loadPW(ch);                               // w2f loads fly under DW
        phaseDW(ch);
        __syncthreads();                          // stg reads done; h2s written; pwreg ready
        if (ch + 1 < 12) dma(ch + 1);             // overwrite stg while P runs
        phaseP();
        __syncthreads();                          // DMA landed; h2s free
    }

    // ---- epilogue: out = x + (proj + be3) * mf ----
    #pragma unroll
    for (int ti = 0; ti < 2; ++ti) {
        if (ti == 1 && !has2) break;
        const int px = (ti == 0 ? t0 : 2 * wv + 1) * 16 + r16;
        const float mv = mfv_[px];
        #pragma unroll
        for (int ot = 0; ot < 8; ++ot) {
            const int ob = ot * 16 + g * 4;
            const float4 be4 = *(const float4*)&be3g[ob];
            const size_t base = (size_t)(b * OUP + ob) * HWSZ + p0 + px;
            out[base]            = x[base]            + (pacc[ti][ot][0] + be4.x) * mv;
            out[base + HWSZ]     = x[base + HWSZ]     + (pacc[ti][ot][1] + be4.y) * mv;
            out[base + 2 * HWSZ] = x[base + 2 * HWSZ] + (pacc[ti][ot][2] + be4.z) * mv;
            out[base + 3 * HWSZ] = x[base + 3 * HWSZ] + (pacc[ti][ot][3] + be4.w) * mv;
        }
    }
}

extern "C" void kernel_launch(void* const* d_in, const int* in_sizes, int n_in,
                              void* d_out, int out_size, void* d_ws, size_t ws_size,
                              hipStream_t stream) {
    (void)in_sizes; (void)n_in; (void)out_size; (void)ws_size;
    const float* x   = (const float*)d_in[0];
    const float* w1  = (const float*)d_in[1];
    const float* g1  = (const float*)d_in[2];
    const float* b1  = (const float*)d_in[3];
    const float* m1  = (const float*)d_in[4];
    const float* v1  = (const float*)d_in[5];
    const float* wdw = (const float*)d_in[6];
    const float* g2  = (const float*)d_in[7];
    const float* b2  = (const float*)d_in[8];
    const float* m2  = (const float*)d_in[9];
    const float* v2  = (const float*)d_in[10];
    const float* w2  = (const float*)d_in[11];
    const float* g3  = (const float*)d_in[12];
    const float* b3  = (const float*)d_in[13];
    const float* m3  = (const float*)d_in[14];
    const float* v3  = (const float*)d_in[15];
    const int*  mask = (const int*)d_in[16];
    float* out = (float*)d_out;

    char* ws = (char*)d_ws;
    unsigned short* w1f = (unsigned short*)ws;                 // 196608 B
    unsigned short* w2f = (unsigned short*)(ws + 196608);      // 196608 B
    float* be1o = (float*)(ws + 393216);                       // 3072 B
    float* wdsf = (float*)(ws + 396288);                       // 27648 B  [9][768]
    float* be2o = (float*)(ws + 423936);                       // 3072 B
    float* be3o = (float*)(ws + 427008);                       // 512 B
    float* mdf  = (float*)(ws + 427520);                       // 200704 B
    float* mff  = (float*)(ws + 628224);                       // 200704 B
    unsigned* h1p = (unsigned*)(ws + 828928);                  // 91226112 B ([b][cp384][58][64] dw)

    prep<<<256, 256, 0, stream>>>(w1, g1, b1, m1, v1, wdw, g2, b2, m2, v2,
                                  w2, g3, b3, m3, v3, mask,
                                  w1f, w2f, be1o, wdsf, be2o, be3o, mdf, mff, h1p);
    k1_expand<<<dim3(1200), 512, 0, stream>>>(x, w1f, be1o, mdf, h1p);
    k23<<<dim3(224), 512, 0, stream>>>(h1p, w2f, wdsf, be2o, be3o, mff, x, out);
}

// Round 18
// 95.036 us; speedup vs baseline: 1.1431x; 1.1431x over previous
//
#include <hip/hip_runtime.h>
#include <hip/hip_bf16.h>

#define BATCH 16
#define INP   128
#define OUP   128
#define HH    56
#define WW    56
#define HWSZ  3136
#define HID   768
#define EPSV  1e-5f

#define RWST  1992            // k23 stg row stride (dw): 8 mod 32 -> row halves de-alias banks
#define H2STR 72              // h2s elem stride (144B)

typedef __attribute__((ext_vector_type(8))) short bf16x8;
typedef __attribute__((ext_vector_type(4))) float f32x4;

__device__ __forceinline__ unsigned short f2b(float f) {
    unsigned u = __float_as_uint(f);
    return (unsigned short)((u + 0x7FFFu + ((u >> 16) & 1u)) >> 16);   // RNE
}
__device__ __forceinline__ float blo(unsigned u){ return __uint_as_float(u << 16); }
__device__ __forceinline__ float bhi(unsigned u){ return __uint_as_float(u & 0xFFFF0000u); }
__device__ __forceinline__ unsigned pkbf(float lo, float hi) {
    unsigned r;
    asm("v_cvt_pk_bf16_f32 %0, %1, %2" : "=v"(r) : "v"(lo), "v"(hi));
    return r;
}

// ---------------- prep: fold BN into bf16 weights (fragment-linear) + mask dilate ----------------
__global__ void prep(const float* __restrict__ w1, const float* __restrict__ g1,
                     const float* __restrict__ b1, const float* __restrict__ m1, const float* __restrict__ v1,
                     const float* __restrict__ wdw, const float* __restrict__ g2,
                     const float* __restrict__ b2, const float* __restrict__ m2, const float* __restrict__ v2,
                     const float* __restrict__ w2, const float* __restrict__ g3,
                     const float* __restrict__ b3, const float* __restrict__ m3, const float* __restrict__ v3,
                     const int* __restrict__ mask,
                     unsigned short* __restrict__ w1f, unsigned short* __restrict__ w2f,
                     float* __restrict__ be1o, float* __restrict__ wdsf,
                     float* __restrict__ be2o, float* __restrict__ be3o,
                     float* __restrict__ mdf, float* __restrict__ mff)
{
    int gid = blockIdx.x * blockDim.x + threadIdx.x;
    int stp = gridDim.x * blockDim.x;
    // w1 fragment-linear: [ht 48][ks 4][g 4][r16 16][e 8]
    for (int i = gid; i < HID * INP; i += stp) {
        int r = i >> 7, k = i & 127;
        float s = g1[r] * rsqrtf(v1[r] + EPSV);
        int ht = r >> 4, r16 = r & 15, ks = k >> 5, g = (k >> 3) & 3, e = k & 7;
        w1f[((((ht * 4 + ks) * 4 + g) * 16 + r16) << 3) + e] = f2b(w1[i] * s);
    }
    // w2 fragment-linear: [ot 8][ch 12][ks 2][lane 64][e 8]
    for (int i = gid; i < OUP * HID; i += stp) {
        int r = i / HID, k = i - r * HID;
        float s = g3[r] * rsqrtf(v3[r] + EPSV);
        int ot = r >> 4, r16 = r & 15, ch = k >> 6, ks = (k >> 5) & 1, g = (k >> 3) & 3, e = k & 7;
        int lane = g * 16 + r16;
        w2f[((((ot * 12 + ch) * 2 + ks) * 64 + lane) << 3) + e] = f2b(w2[i] * s);
    }
    for (int i = gid; i < HID; i += stp) {
        float s1 = g1[i] * rsqrtf(v1[i] + EPSV);
        be1o[i] = b1[i] - m1[i] * s1;
        float s2 = g2[i] * rsqrtf(v2[i] + EPSV);
        be2o[i] = b2[i] - m2[i] * s2;
    }
    for (int i = gid; i < HID * 9; i += stp) {          // tap-major [q][c], BN2 scale folded
        int q = i / HID, c = i - q * HID;
        float s2 = g2[c] * rsqrtf(v2[c] + EPSV);
        wdsf[i] = wdw[c * 9 + q] * s2;
    }
    for (int i = gid; i < OUP; i += stp) {
        float s3 = g3[i] * rsqrtf(v3[i] + EPSV);
        be3o[i] = b3[i] - m3[i] * s3;
    }
    for (int i = gid; i < BATCH * HWSZ; i += stp) {     // mf + 3x3 dilated md
        int b = i / HWSZ, p = i - b * HWSZ;
        int y = p / WW, xx = p - y * WW;
        float mf = (float)mask[i];
        float md = 0.f;
        for (int dy = -1; dy <= 1; ++dy)
            for (int dx = -1; dx <= 1; ++dx) {
                int yy = y + dy, xc = xx + dx;
                if (yy >= 0 && yy < HH && xc >= 0 && xc < WW)
                    md = fmaxf(md, (float)mask[b * HWSZ + yy * WW + xc]);
            }
        mff[i] = mf;
        mdf[i] = md;
    }
}

// ---------------- K1: expand GEMM -> h1 (bf16 pair-interleaved [b][c/2][p]) — r10/r13 proven ----------------
__launch_bounds__(512, 4)
__global__ void k1_expand(const float* __restrict__ x,
                          const unsigned short* __restrict__ w1f,
                          const float* __restrict__ be1g,
                          const float* __restrict__ mdf,
                          unsigned* __restrict__ h1p)
{
    __shared__ unsigned short xs[128 * 128];   // 32 KB  bf16 x-tile [px][c] swizzled
    const int t = threadIdx.x, lane = t & 63, wv = t >> 6;
    const int g = lane >> 4, r16 = lane & 15;
    const int pid = blockIdx.x;
    const int l = (pid & 7) * 150 + (pid >> 3);
    const int hb = l % 3;
    const int pb = (l / 3) % 25;
    const int b  = l / 75;
    const int p0 = pb * 128;
    const int whid = wv & 3;
    const int wpx  = wv >> 2;

    for (int rep = 0; rep < 8; ++rep) {
        int id = t + rep * 512;
        int px = id & 127, c4 = id >> 7;
        int p = p0 + px;
        ushort4 u; u.x = 0; u.y = 0; u.z = 0; u.w = 0;
        if (p < HWSZ) {
            const float* xp = x + ((size_t)(b * INP + c4 * 4)) * HWSZ + p;
            unsigned lo = pkbf(xp[0], xp[HWSZ]);
            unsigned hi = pkbf(xp[2 * HWSZ], xp[3 * HWSZ]);
            u.x = (unsigned short)lo; u.y = (unsigned short)(lo >> 16);
            u.z = (unsigned short)hi; u.w = (unsigned short)(hi >> 16);
        }
        *(ushort4*)&xs[px * 128 + (((c4 >> 1) ^ (px & 15)) << 3) + ((c4 & 1) << 2)] = u;
    }
    __syncthreads();

    f32x4 acc[4][4];
    #pragma unroll
    for (int mt = 0; mt < 4; ++mt)
        #pragma unroll
        for (int nt = 0; nt < 4; ++nt) {
            acc[mt][nt][0] = 0.f; acc[mt][nt][1] = 0.f;
            acc[mt][nt][2] = 0.f; acc[mt][nt][3] = 0.f;
        }
    const int hbase = hb * 256 + whid * 64;
    const int htb = hbase >> 4;

    #pragma unroll
    for (int ks = 0; ks < 4; ++ks) {
        bf16x8 af[4];
        #pragma unroll
        for (int mt = 0; mt < 4; ++mt)
            af[mt] = *(const bf16x8*)&w1f[((((htb + mt) * 4 + ks) * 64) + lane) << 3];
        #pragma unroll
        for (int nt = 0; nt < 4; ++nt) {
            int px = wpx * 64 + nt * 16 + r16;
            bf16x8 bf = *(const bf16x8*)&xs[px * 128 + (((ks * 4 + g) ^ r16) << 3)];
            #pragma unroll
            for (int mt = 0; mt < 4; ++mt)
                acc[mt][nt] = __builtin_amdgcn_mfma_f32_16x16x32_bf16(af[mt], bf, acc[mt][nt], 0, 0, 0);
        }
    }

    #pragma unroll
    for (int nt = 0; nt < 4; ++nt) {
        const int pg = p0 + wpx * 64 + nt * 16;
        if (pg >= HWSZ) continue;
        const int p = pg + r16;
        const float md = mdf[b * HWSZ + p];
        #pragma unroll
        for (int mt = 0; mt < 4; ++mt) {
            const float4 be4 = *(const float4*)&be1g[hbase + mt * 16 + g * 4];
            f32x4 a = acc[mt][nt];
            float v0 = fminf(fmaxf(a[0] + be4.x, 0.f), 6.f) * md;
            float v1 = fminf(fmaxf(a[1] + be4.y, 0.f), 6.f) * md;
            float v2 = fminf(fmaxf(a[2] + be4.z, 0.f), 6.f) * md;
            float v3 = fminf(fmaxf(a[3] + be4.w, 0.f), 6.f) * md;
            const int c2 = (hbase >> 1) + mt * 8 + g * 2;
            const size_t ad = (size_t)(b * 384 + c2) * HWSZ + p;
            h1p[ad] = pkbf(v0, v1);
            h1p[ad + HWSZ] = pkbf(v2, v3);
        }
    }
}

// ---------------- K23: r13 structure + w2f register prefetch during DW ----------------
__launch_bounds__(512, 4)
__global__ void k23(const unsigned* __restrict__ h1p,
                    const unsigned short* __restrict__ w2f,
                    const float* __restrict__ wdsf,
                    const float* __restrict__ be2g,
                    const float* __restrict__ be3g,
                    const float* __restrict__ mff,
                    const float* __restrict__ x,
                    float* __restrict__ out)
{
    __shared__ unsigned stg[4 * RWST];           // 31872 B  h1 rows [row 4][cp 32 x 62 dw]
    __shared__ unsigned short h2s[112 * H2STR];  // 16128 B  h2 [px][c] swizzled
    __shared__ float mfv_[112];                  //   448 B

    const int t = threadIdx.x, lane = t & 63, wv = t >> 6;
    const int g = lane >> 4, r16 = lane & 15;
    const int pid = blockIdx.x;
    const int l = (pid & 7) * 56 + (pid >> 3);   // XCD swizzle (448 = 8*56)
    const int strip = l % 28, b = l / 28;
    const int y0 = strip * 2, p0 = strip * 112;

    // ---------------- prologue ----------------
    if (t < 112) mfv_[t] = mff[b * HWSZ + p0 + t];
    if (t >= 128 && t < 384) {   // zero stg edge dwords (px=-1 at off 1, px=56 at off 58)
        int i = t - 128;
        int cp = i & 31, rs = (i >> 5) & 3, side = (i >> 7) & 1;
        stg[rs * RWST + cp * 62 + (side ? 58 : 1)] = 0;
    }

    // T14 stage state (r10 proven): 1792 tasks = cp32 x row4 x px4_14
    int gaddr[4], laddr[4]; bool gval[4], wval[4];
    #pragma unroll
    for (int rep = 0; rep < 4; ++rep) {
        const int id = t + rep * 512;
        const int rr  = (id * 4682) >> 16;            // id/14
        const int px4 = id - rr * 14;
        const int row = rr & 3, cp = rr >> 2;
        const int gy = y0 - 1 + row;
        wval[rep] = id < 1792;
        gval[rep] = wval[rep] && gy >= 0 && gy < HH;
        gaddr[rep] = (b * 384 + cp) * HWSZ + gy * WW + px4 * 4;
        laddr[rep] = row * RWST + cp * 62 + 2 + px4 * 4;
    }
    uint4 sreg[4];

    auto issueLoads = [&]() {
        #pragma unroll
        for (int rep = 0; rep < 4; ++rep) {
            uint4 u; u.x = 0; u.y = 0; u.z = 0; u.w = 0;
            if (gval[rep]) u = *(const uint4*)&h1p[gaddr[rep]];
            sreg[rep] = u;
            gaddr[rep] += 32 * HWSZ;                  // next chunk (+32 cp)
        }
    };
    auto stageWrite = [&]() {
        #pragma unroll
        for (int rep = 0; rep < 4; ++rep) {
            if (wval[rep]) {
                unsigned* s = &stg[laddr[rep]];
                uint2 a; a.x = sreg[rep].x; a.y = sreg[rep].y;
                uint2 c; c.x = sreg[rep].z; c.y = sreg[rep].w;
                *(uint2*)(s) = a;
                *(uint2*)(s + 2) = c;
            }
        }
    };

    // DW mapping: thread -> (cp 32, row2 2, q 8); 2 paired channels x 7 px each
    const int cp_c = t & 31, row2 = (t >> 5) & 1, q = t >> 6;   // q == wave id
    unsigned* const h2d = (unsigned*)h2s;

    auto phaseDW = [&](int ch) {
        const float2 be2 = *(const float2*)&be2g[ch * 64 + 2 * cp_c];
        float accL[7], accH[7];
        #pragma unroll
        for (int j = 0; j < 7; ++j) { accL[j] = be2.x; accH[j] = be2.y; }
        #pragma unroll
        for (int dy = 0; dy < 3; ++dy) {
            const float2 wt0 = *(const float2*)&wdsf[(dy * 3 + 0) * HID + ch * 64 + 2 * cp_c];
            const float2 wt1 = *(const float2*)&wdsf[(dy * 3 + 1) * HID + ch * 64 + 2 * cp_c];
            const float2 wt2 = *(const float2*)&wdsf[(dy * 3 + 2) * HID + ch * 64 + 2 * cp_c];
            const unsigned* rp = &stg[(row2 + dy) * RWST + cp_c * 62 + 1 + q * 7];
            float pL[9], pH[9];
            #pragma unroll
            for (int k = 0; k < 9; ++k) {
                unsigned u = rp[k];
                pL[k] = blo(u); pH[k] = bhi(u);
            }
            #pragma unroll
            for (int j = 0; j < 7; ++j) {
                accL[j] += pL[j] * wt0.x + pL[j + 1] * wt1.x + pL[j + 2] * wt2.x;
                accH[j] += pH[j] * wt0.y + pH[j + 1] * wt1.y + pH[j + 2] * wt2.y;
            }
        }
        #pragma unroll
        for (int j = 0; j < 7; ++j) {
            const int px = row2 * 56 + q * 7 + j;
            const float mv = mfv_[px];
            float vL = __builtin_amdgcn_fmed3f(accL[j], 0.f, 6.f) * mv;
            float vH = __builtin_amdgcn_fmed3f(accH[j], 0.f, 6.f) * mv;
            // full-dword write at P-read-compatible slot: octet (cp>>2)^(px&7), dword (cp&3)
            h2d[px * 36 + (((cp_c >> 2) ^ (px & 7)) << 2) + (cp_c & 3)] = pkbf(vL, vH);
        }
    };

    f32x4 pacc[7];
    #pragma unroll
    for (int nt = 0; nt < 7; ++nt) {
        pacc[nt][0] = 0.f; pacc[nt][1] = 0.f; pacc[nt][2] = 0.f; pacc[nt][3] = 0.f;
    }

    bf16x8 pwreg[2];                              // this chunk's w2f fragments (prefetched)
    auto loadPW = [&](int ch) {
        #pragma unroll
        for (int ks = 0; ks < 2; ++ks)
            pwreg[ks] = *(const bf16x8*)&w2f[((((wv * 12 + ch) * 2 + ks) * 64) + lane) << 3];
    };

    auto phaseP = [&]() {
        #pragma unroll
        for (int ks = 0; ks < 2; ++ks) {
            #pragma unroll
            for (int nt = 0; nt < 7; ++nt) {
                const int px = nt * 16 + r16;
                const bf16x8 hb = *(const bf16x8*)&h2s[px * H2STR + (((ks * 4 + g) ^ (px & 7)) << 3)];
                pacc[nt] = __builtin_amdgcn_mfma_f32_16x16x32_bf16(pwreg[ks], hb, pacc[nt], 0, 0, 0);
            }
        }
    };

    // ---- main loop: loads for ch+1 fly under DW(ch); write lands under P(ch) ----
    issueLoads();
    stageWrite();
    __syncthreads();
    for (int ch = 0; ch < 12; ++ch) {
        if (ch + 1 < 12) issueLoads();
        loadPW(ch);                           // w2f L2 loads hidden under DW
        phaseDW(ch);
        __syncthreads();                      // stg reads done; h2s written
        if (ch + 1 < 12) stageWrite();
        phaseP();
        __syncthreads();                      // stg ready; h2s free
    }

    // ---- epilogue: out = x + (proj + be3) * mf ----
    {
        const int ob = wv * 16 + g * 4;
        const float4 be4 = *(const float4*)&be3g[ob];
        #pragma unroll
        for (int nt = 0; nt < 7; ++nt) {
            const int px = nt * 16 + r16;
            const float mv = mfv_[px];
            const size_t base = (size_t)(b * OUP + ob) * HWSZ + p0 + px;
            out[base]            = x[base]            + (pacc[nt][0] + be4.x) * mv;
            out[base + HWSZ]     = x[base + HWSZ]     + (pacc[nt][1] + be4.y) * mv;
            out[base + 2 * HWSZ] = x[base + 2 * HWSZ] + (pacc[nt][2] + be4.z) * mv;
            out[base + 3 * HWSZ] = x[base + 3 * HWSZ] + (pacc[nt][3] + be4.w) * mv;
        }
    }
}

extern "C" void kernel_launch(void* const* d_in, const int* in_sizes, int n_in,
                              void* d_out, int out_size, void* d_ws, size_t ws_size,
                              hipStream_t stream) {
    (void)in_sizes; (void)n_in; (void)out_size; (void)ws_size;
    const float* x   = (const float*)d_in[0];
    const float* w1  = (const float*)d_in[1];
    const float* g1  = (const float*)d_in[2];
    const float* b1  = (const float*)d_in[3];
    const float* m1  = (const float*)d_in[4];
    const float* v1  = (const float*)d_in[5];
    const float* wdw = (const float*)d_in[6];
    const float* g2  = (const float*)d_in[7];
    const float* b2  = (const float*)d_in[8];
    const float* m2  = (const float*)d_in[9];
    const float* v2  = (const float*)d_in[10];
    const float* w2  = (const float*)d_in[11];
    const float* g3  = (const float*)d_in[12];
    const float* b3  = (const float*)d_in[13];
    const float* m3  = (const float*)d_in[14];
    const float* v3  = (const float*)d_in[15];
    const int*  mask = (const int*)d_in[16];
    float* out = (float*)d_out;

    char* ws = (char*)d_ws;
    unsigned short* w1f = (unsigned short*)ws;                 // 196608 B
    unsigned short* w2f = (unsigned short*)(ws + 196608);      // 196608 B
    float* be1o = (float*)(ws + 393216);                       // 3072 B
    float* wdsf = (float*)(ws + 396288);                       // 27648 B  [9][768]
    float* be2o = (float*)(ws + 423936);                       // 3072 B
    float* be3o = (float*)(ws + 427008);                       // 512 B
    float* mdf  = (float*)(ws + 427520);                       // 200704 B
    float* mff  = (float*)(ws + 628224);                       // 200704 B
    unsigned* h1p = (unsigned*)(ws + 828928);                  // 77070336 B (bf16 pairs)

    prep<<<256, 256, 0, stream>>>(w1, g1, b1, m1, v1, wdw, g2, b2, m2, v2,
                                  w2, g3, b3, m3, v3, mask,
                                  w1f, w2f, be1o, wdsf, be2o, be3o, mdf, mff);
    k1_expand<<<dim3(1200), 512, 0, stream>>>(x, w1f, be1o, mdf, h1p);
    k23<<<dim3(448), 512, 0, stream>>>(h1p, w2f, wdsf, be2o, be3o, mff, x, out);
}

// Round 19
// 91.012 us; speedup vs baseline: 1.1936x; 1.0442x over previous
//
#include <hip/hip_runtime.h>
#include <hip/hip_bf16.h>

#define BATCH 16
#define INP   128
#define OUP   128
#define HH    56
#define WW    56
#define HWSZ  3136
#define HID   768
#define EPSV  1e-5f

#define RWST  1992            // k23 stg row stride (dw): 8 mod 32 -> row halves de-alias banks
#define H2STR 72              // h2s elem stride (144B)

typedef __attribute__((ext_vector_type(8))) short bf16x8;
typedef __attribute__((ext_vector_type(4))) float f32x4;

// lgkm-only barrier: LDS ordering without draining in-flight global loads (vmcnt)
#define BARRIER_LGKM() asm volatile("s_waitcnt lgkmcnt(0)\ns_barrier" ::: "memory")

__device__ __forceinline__ unsigned short f2b(float f) {
    unsigned u = __float_as_uint(f);
    return (unsigned short)((u + 0x7FFFu + ((u >> 16) & 1u)) >> 16);   // RNE
}
__device__ __forceinline__ float blo(unsigned u){ return __uint_as_float(u << 16); }
__device__ __forceinline__ float bhi(unsigned u){ return __uint_as_float(u & 0xFFFF0000u); }
__device__ __forceinline__ unsigned pkbf(float lo, float hi) {
    unsigned r;
    asm("v_cvt_pk_bf16_f32 %0, %1, %2" : "=v"(r) : "v"(lo), "v"(hi));
    return r;
}

// ---------------- prep: fold BN into bf16 weights (fragment-linear) + mask dilate ----------------
__global__ void prep(const float* __restrict__ w1, const float* __restrict__ g1,
                     const float* __restrict__ b1, const float* __restrict__ m1, const float* __restrict__ v1,
                     const float* __restrict__ wdw, const float* __restrict__ g2,
                     const float* __restrict__ b2, const float* __restrict__ m2, const float* __restrict__ v2,
                     const float* __restrict__ w2, const float* __restrict__ g3,
                     const float* __restrict__ b3, const float* __restrict__ m3, const float* __restrict__ v3,
                     const int* __restrict__ mask,
                     unsigned short* __restrict__ w1f, unsigned short* __restrict__ w2f,
                     float* __restrict__ be1o, float* __restrict__ wdsf,
                     float* __restrict__ be2o, float* __restrict__ be3o,
                     float* __restrict__ mdf, float* __restrict__ mff)
{
    int gid = blockIdx.x * blockDim.x + threadIdx.x;
    int stp = gridDim.x * blockDim.x;
    // w1 fragment-linear: [ht 48][ks 4][g 4][r16 16][e 8]
    for (int i = gid; i < HID * INP; i += stp) {
        int r = i >> 7, k = i & 127;
        float s = g1[r] * rsqrtf(v1[r] + EPSV);
        int ht = r >> 4, r16 = r & 15, ks = k >> 5, g = (k >> 3) & 3, e = k & 7;
        w1f[((((ht * 4 + ks) * 4 + g) * 16 + r16) << 3) + e] = f2b(w1[i] * s);
    }
    // w2 fragment-linear: [ot 8][ch 12][ks 2][lane 64][e 8]
    for (int i = gid; i < OUP * HID; i += stp) {
        int r = i / HID, k = i - r * HID;
        float s = g3[r] * rsqrtf(v3[r] + EPSV);
        int ot = r >> 4, r16 = r & 15, ch = k >> 6, ks = (k >> 5) & 1, g = (k >> 3) & 3, e = k & 7;
        int lane = g * 16 + r16;
        w2f[((((ot * 12 + ch) * 2 + ks) * 64 + lane) << 3) + e] = f2b(w2[i] * s);
    }
    for (int i = gid; i < HID; i += stp) {
        float s1 = g1[i] * rsqrtf(v1[i] + EPSV);
        be1o[i] = b1[i] - m1[i] * s1;
        float s2 = g2[i] * rsqrtf(v2[i] + EPSV);
        be2o[i] = b2[i] - m2[i] * s2;
    }
    for (int i = gid; i < HID * 9; i += stp) {          // tap-major [q][c], BN2 scale folded
        int q = i / HID, c = i - q * HID;
        float s2 = g2[c] * rsqrtf(v2[c] + EPSV);
        wdsf[i] = wdw[c * 9 + q] * s2;
    }
    for (int i = gid; i < OUP; i += stp) {
        float s3 = g3[i] * rsqrtf(v3[i] + EPSV);
        be3o[i] = b3[i] - m3[i] * s3;
    }
    for (int i = gid; i < BATCH * HWSZ; i += stp) {     // mf + 3x3 dilated md
        int b = i / HWSZ, p = i - b * HWSZ;
        int y = p / WW, xx = p - y * WW;
        float mf = (float)mask[i];
        float md = 0.f;
        for (int dy = -1; dy <= 1; ++dy)
            for (int dx = -1; dx <= 1; ++dx) {
                int yy = y + dy, xc = xx + dx;
                if (yy >= 0 && yy < HH && xc >= 0 && xc < WW)
                    md = fmaxf(md, (float)mask[b * HWSZ + yy * WW + xc]);
            }
        mff[i] = mf;
        mdf[i] = md;
    }
}

// ---------------- K1: expand GEMM -> h1 (bf16 pair-interleaved [b][c/2][p]) — r10/r13 proven ----------------
__launch_bounds__(512, 4)
__global__ void k1_expand(const float* __restrict__ x,
                          const unsigned short* __restrict__ w1f,
                          const float* __restrict__ be1g,
                          const float* __restrict__ mdf,
                          unsigned* __restrict__ h1p)
{
    __shared__ unsigned short xs[128 * 128];   // 32 KB  bf16 x-tile [px][c] swizzled
    const int t = threadIdx.x, lane = t & 63, wv = t >> 6;
    const int g = lane >> 4, r16 = lane & 15;
    const int pid = blockIdx.x;
    const int l = (pid & 7) * 150 + (pid >> 3);
    const int hb = l % 3;
    const int pb = (l / 3) % 25;
    const int b  = l / 75;
    const int p0 = pb * 128;
    const int whid = wv & 3;
    const int wpx  = wv >> 2;

    for (int rep = 0; rep < 8; ++rep) {
        int id = t + rep * 512;
        int px = id & 127, c4 = id >> 7;
        int p = p0 + px;
        ushort4 u; u.x = 0; u.y = 0; u.z = 0; u.w = 0;
        if (p < HWSZ) {
            const float* xp = x + ((size_t)(b * INP + c4 * 4)) * HWSZ + p;
            unsigned lo = pkbf(xp[0], xp[HWSZ]);
            unsigned hi = pkbf(xp[2 * HWSZ], xp[3 * HWSZ]);
            u.x = (unsigned short)lo; u.y = (unsigned short)(lo >> 16);
            u.z = (unsigned short)hi; u.w = (unsigned short)(hi >> 16);
        }
        *(ushort4*)&xs[px * 128 + (((c4 >> 1) ^ (px & 15)) << 3) + ((c4 & 1) << 2)] = u;
    }
    __syncthreads();

    f32x4 acc[4][4];
    #pragma unroll
    for (int mt = 0; mt < 4; ++mt)
        #pragma unroll
        for (int nt = 0; nt < 4; ++nt) {
            acc[mt][nt][0] = 0.f; acc[mt][nt][1] = 0.f;
            acc[mt][nt][2] = 0.f; acc[mt][nt][3] = 0.f;
        }
    const int hbase = hb * 256 + whid * 64;
    const int htb = hbase >> 4;

    #pragma unroll
    for (int ks = 0; ks < 4; ++ks) {
        bf16x8 af[4];
        #pragma unroll
        for (int mt = 0; mt < 4; ++mt)
            af[mt] = *(const bf16x8*)&w1f[((((htb + mt) * 4 + ks) * 64) + lane) << 3];
        #pragma unroll
        for (int nt = 0; nt < 4; ++nt) {
            int px = wpx * 64 + nt * 16 + r16;
            bf16x8 bf = *(const bf16x8*)&xs[px * 128 + (((ks * 4 + g) ^ r16) << 3)];
            #pragma unroll
            for (int mt = 0; mt < 4; ++mt)
                acc[mt][nt] = __builtin_amdgcn_mfma_f32_16x16x32_bf16(af[mt], bf, acc[mt][nt], 0, 0, 0);
        }
    }

    #pragma unroll
    for (int nt = 0; nt < 4; ++nt) {
        const int pg = p0 + wpx * 64 + nt * 16;
        if (pg >= HWSZ) continue;
        const int p = pg + r16;
        const float md = mdf[b * HWSZ + p];
        #pragma unroll
        for (int mt = 0; mt < 4; ++mt) {
            const float4 be4 = *(const float4*)&be1g[hbase + mt * 16 + g * 4];
            f32x4 a = acc[mt][nt];
            float v0 = fminf(fmaxf(a[0] + be4.x, 0.f), 6.f) * md;
            float v1 = fminf(fmaxf(a[1] + be4.y, 0.f), 6.f) * md;
            float v2 = fminf(fmaxf(a[2] + be4.z, 0.f), 6.f) * md;
            float v3 = fminf(fmaxf(a[3] + be4.w, 0.f), 6.f) * md;
            const int c2 = (hbase >> 1) + mt * 8 + g * 2;
            const size_t ad = (size_t)(b * 384 + c2) * HWSZ + p;
            h1p[ad] = pkbf(v0, v1);
            h1p[ad + HWSZ] = pkbf(v2, v3);
        }
    }
}

// ---------------- K23: r13 structure + lgkm-only barriers + stageWrite after P ----------------
__launch_bounds__(512, 4)
__global__ void k23(const unsigned* __restrict__ h1p,
                    const unsigned short* __restrict__ w2f,
                    const float* __restrict__ wdsf,
                    const float* __restrict__ be2g,
                    const float* __restrict__ be3g,
                    const float* __restrict__ mff,
                    const float* __restrict__ x,
                    float* __restrict__ out)
{
    __shared__ unsigned stg[4 * RWST];           // 31872 B  h1 rows [row 4][cp 32 x 62 dw]
    __shared__ unsigned short h2s[112 * H2STR];  // 16128 B  h2 [px][c] swizzled
    __shared__ float mfv_[112];                  //   448 B

    const int t = threadIdx.x, lane = t & 63, wv = t >> 6;
    const int g = lane >> 4, r16 = lane & 15;
    const int pid = blockIdx.x;
    const int l = (pid & 7) * 56 + (pid >> 3);   // XCD swizzle (448 = 8*56)
    const int strip = l % 28, b = l / 28;
    const int y0 = strip * 2, p0 = strip * 112;

    // ---------------- prologue ----------------
    if (t < 112) mfv_[t] = mff[b * HWSZ + p0 + t];
    if (t >= 128 && t < 384) {   // zero stg edge dwords (px=-1 at off 1, px=56 at off 58)
        int i = t - 128;
        int cp = i & 31, rs = (i >> 5) & 3, side = (i >> 7) & 1;
        stg[rs * RWST + cp * 62 + (side ? 58 : 1)] = 0;
    }

    // T14 stage state: 1792 tasks = cp32 x row4 x px4_14
    int gaddr[4], laddr[4]; bool gval[4], wval[4];
    #pragma unroll
    for (int rep = 0; rep < 4; ++rep) {
        const int id = t + rep * 512;
        const int rr  = (id * 4682) >> 16;            // id/14
        const int px4 = id - rr * 14;
        const int row = rr & 3, cp = rr >> 2;
        const int gy = y0 - 1 + row;
        wval[rep] = id < 1792;
        gval[rep] = wval[rep] && gy >= 0 && gy < HH;
        gaddr[rep] = (b * 384 + cp) * HWSZ + gy * WW + px4 * 4;
        laddr[rep] = row * RWST + cp * 62 + 2 + px4 * 4;
    }
    uint4 sreg[4];

    auto issueLoads = [&]() {
        #pragma unroll
        for (int rep = 0; rep < 4; ++rep) {
            uint4 u; u.x = 0; u.y = 0; u.z = 0; u.w = 0;
            if (gval[rep]) u = *(const uint4*)&h1p[gaddr[rep]];
            sreg[rep] = u;
            gaddr[rep] += 32 * HWSZ;                  // next chunk (+32 cp)
        }
    };
    auto stageWrite = [&]() {
        #pragma unroll
        for (int rep = 0; rep < 4; ++rep) {
            if (wval[rep]) {
                unsigned* s = &stg[laddr[rep]];
                uint2 a; a.x = sreg[rep].x; a.y = sreg[rep].y;
                uint2 c; c.x = sreg[rep].z; c.y = sreg[rep].w;
                *(uint2*)(s) = a;
                *(uint2*)(s + 2) = c;
            }
        }
    };

    // DW mapping: thread -> (cp 32, row2 2, q 8); 2 paired channels x 7 px each
    const int cp_c = t & 31, row2 = (t >> 5) & 1, q = t >> 6;   // q == wave id
    unsigned* const h2d = (unsigned*)h2s;

    auto phaseDW = [&](int ch) {
        const float2 be2 = *(const float2*)&be2g[ch * 64 + 2 * cp_c];
        float accL[7], accH[7];
        #pragma unroll
        for (int j = 0; j < 7; ++j) { accL[j] = be2.x; accH[j] = be2.y; }
        #pragma unroll
        for (int dy = 0; dy < 3; ++dy) {
            const float2 wt0 = *(const float2*)&wdsf[(dy * 3 + 0) * HID + ch * 64 + 2 * cp_c];
            const float2 wt1 = *(const float2*)&wdsf[(dy * 3 + 1) * HID + ch * 64 + 2 * cp_c];
            const float2 wt2 = *(const float2*)&wdsf[(dy * 3 + 2) * HID + ch * 64 + 2 * cp_c];
            const unsigned* rp = &stg[(row2 + dy) * RWST + cp_c * 62 + 1 + q * 7];
            float pL[9], pH[9];
            #pragma unroll
            for (int k = 0; k < 9; ++k) {
                unsigned u = rp[k];
                pL[k] = blo(u); pH[k] = bhi(u);
            }
            #pragma unroll
            for (int j = 0; j < 7; ++j) {
                accL[j] += pL[j] * wt0.x + pL[j + 1] * wt1.x + pL[j + 2] * wt2.x;
                accH[j] += pH[j] * wt0.y + pH[j + 1] * wt1.y + pH[j + 2] * wt2.y;
            }
        }
        #pragma unroll
        for (int j = 0; j < 7; ++j) {
            const int px = row2 * 56 + q * 7 + j;
            const float mv = mfv_[px];
            float vL = __builtin_amdgcn_fmed3f(accL[j], 0.f, 6.f) * mv;
            float vH = __builtin_amdgcn_fmed3f(accH[j], 0.f, 6.f) * mv;
            // full-dword write at P-read-compatible slot: octet (cp>>2)^(px&7), dword (cp&3)
            h2d[px * 36 + (((cp_c >> 2) ^ (px & 7)) << 2) + (cp_c & 3)] = pkbf(vL, vH);
        }
    };

    f32x4 pacc[7];
    #pragma unroll
    for (int nt = 0; nt < 7; ++nt) {
        pacc[nt][0] = 0.f; pacc[nt][1] = 0.f; pacc[nt][2] = 0.f; pacc[nt][3] = 0.f;
    }

    auto phaseP = [&](int ch) {
        #pragma unroll
        for (int ks = 0; ks < 2; ++ks) {
            const bf16x8 pw = *(const bf16x8*)&w2f[((((wv * 12 + ch) * 2 + ks) * 64) + lane) << 3];
            #pragma unroll
            for (int nt = 0; nt < 7; ++nt) {
                const int px = nt * 16 + r16;
                const bf16x8 hb = *(const bf16x8*)&h2s[px * H2STR + (((ks * 4 + g) ^ (px & 7)) << 3)];
                pacc[nt] = __builtin_amdgcn_mfma_f32_16x16x32_bf16(pw, hb, pacc[nt], 0, 0, 0);
            }
        }
    };

    // ---- main loop: loads(ch+1) fly across barrier (lgkm-only); land at stageWrite after P ----
    issueLoads();
    stageWrite();
    __syncthreads();
    for (int ch = 0; ch < 12; ++ch) {
        if (ch + 1 < 12) issueLoads();        // ~full chunk (DW + bar + P) to cover HBM latency
        phaseDW(ch);
        BARRIER_LGKM();                       // h2s visible, stg reads done; vmcnt NOT drained
        phaseP(ch);
        if (ch + 1 < 12) stageWrite();        // vmcnt waited here by sreg use
        BARRIER_LGKM();                       // stg writes visible for DW(ch+1)
    }

    // ---- epilogue: out = x + (proj + be3) * mf ----
    {
        const int ob = wv * 16 + g * 4;
        const float4 be4 = *(const float4*)&be3g[ob];
        #pragma unroll
        for (int nt = 0; nt < 7; ++nt) {
            const int px = nt * 16 + r16;
            const float mv = mfv_[px];
            const size_t base = (size_t)(b * OUP + ob) * HWSZ + p0 + px;
            out[base]            = x[base]            + (pacc[nt][0] + be4.x) * mv;
            out[base + HWSZ]     = x[base + HWSZ]     + (pacc[nt][1] + be4.y) * mv;
            out[base + 2 * HWSZ] = x[base + 2 * HWSZ] + (pacc[nt][2] + be4.z) * mv;
            out[base + 3 * HWSZ] = x[base + 3 * HWSZ] + (pacc[nt][3] + be4.w) * mv;
        }
    }
}

extern "C" void kernel_launch(void* const* d_in, const int* in_sizes, int n_in,
                              void* d_out, int out_size, void* d_ws, size_t ws_size,
                              hipStream_t stream) {
    (void)in_sizes; (void)n_in; (void)out_size; (void)ws_size;
    const float* x   = (const float*)d_in[0];
    const float* w1  = (const float*)d_in[1];
    const float* g1  = (const float*)d_in[2];
    const float* b1  = (const float*)d_in[3];
    const float* m1  = (const float*)d_in[4];
    const float* v1  = (const float*)d_in[5];
    const float* wdw = (const float*)d_in[6];
    const float* g2  = (const float*)d_in[7];
    const float* b2  = (const float*)d_in[8];
    const float* m2  = (const float*)d_in[9];
    const float* v2  = (const float*)d_in[10];
    const float* w2  = (const float*)d_in[11];
    const float* g3  = (const float*)d_in[12];
    const float* b3  = (const float*)d_in[13];
    const float* m3  = (const float*)d_in[14];
    const float* v3  = (const float*)d_in[15];
    const int*  mask = (const int*)d_in[16];
    float* out = (float*)d_out;

    char* ws = (char*)d_ws;
    unsigned short* w1f = (unsigned short*)ws;                 // 196608 B
    unsigned short* w2f = (unsigned short*)(ws + 196608);      // 196608 B
    float* be1o = (float*)(ws + 393216);                       // 3072 B
    float* wdsf = (float*)(ws + 396288);                       // 27648 B  [9][768]
    float* be2o = (float*)(ws + 423936);                       // 3072 B
    float* be3o = (float*)(ws + 427008);                       // 512 B
    float* mdf  = (float*)(ws + 427520);                       // 200704 B
    float* mff  = (float*)(ws + 628224);                       // 200704 B
    unsigned* h1p = (unsigned*)(ws + 828928);                  // 77070336 B (bf16 pairs)

    prep<<<256, 256, 0, stream>>>(w1, g1, b1, m1, v1, wdw, g2, b2, m2, v2,
                                  w2, g3, b3, m3, v3, mask,
                                  w1f, w2f, be1o, wdsf, be2o, be3o, mdf, mff);
    k1_expand<<<dim3(1200), 512, 0, stream>>>(x, w1f, be1o, mdf, h1p);
    k23<<<dim3(448), 512, 0, stream>>>(h1p, w2f, wdsf, be2o, be3o, mff, x, out);
}

// Round 20
// 88.033 us; speedup vs baseline: 1.2340x; 1.0338x over previous
//
#include <hip/hip_runtime.h>
#include <hip/hip_bf16.h>

#define BATCH 16
#define INP   128
#define OUP   128
#define HH    56
#define WW    56
#define HWSZ  3136
#define HID   768
#define EPSV  1e-5f

#define RWST  1992            // k23 stg row stride (dw): 8 mod 32 -> row halves de-alias banks
#define H2STR 72              // h2s elem stride (144B)

typedef __attribute__((ext_vector_type(8))) short bf16x8;
typedef __attribute__((ext_vector_type(4))) float f32x4;

__device__ __forceinline__ unsigned short f2b(float f) {
    unsigned u = __float_as_uint(f);
    return (unsigned short)((u + 0x7FFFu + ((u >> 16) & 1u)) >> 16);   // RNE
}
__device__ __forceinline__ float blo(unsigned u){ return __uint_as_float(u << 16); }
__device__ __forceinline__ float bhi(unsigned u){ return __uint_as_float(u & 0xFFFF0000u); }
__device__ __forceinline__ unsigned pkbf(float lo, float hi) {
    unsigned r;
    asm("v_cvt_pk_bf16_f32 %0, %1, %2" : "=v"(r) : "v"(lo), "v"(hi));
    return r;
}

// ---------------- prep: fold BN into bf16 weights (fragment-linear) + mask dilate ----------------
__global__ void prep(const float* __restrict__ w1, const float* __restrict__ g1,
                     const float* __restrict__ b1, const float* __restrict__ m1, const float* __restrict__ v1,
                     const float* __restrict__ wdw, const float* __restrict__ g2,
                     const float* __restrict__ b2, const float* __restrict__ m2, const float* __restrict__ v2,
                     const float* __restrict__ w2, const float* __restrict__ g3,
                     const float* __restrict__ b3, const float* __restrict__ m3, const float* __restrict__ v3,
                     const int* __restrict__ mask,
                     unsigned short* __restrict__ w1f, unsigned short* __restrict__ w2f,
                     float* __restrict__ be1o, float* __restrict__ wdsf,
                     float* __restrict__ be2o, float* __restrict__ be3o,
                     float* __restrict__ mdf, float* __restrict__ mff)
{
    int gid = blockIdx.x * blockDim.x + threadIdx.x;
    int stp = gridDim.x * blockDim.x;
    // w1 fragment-linear: [ht 48][ks 4][g 4][r16 16][e 8]
    for (int i = gid; i < HID * INP; i += stp) {
        int r = i >> 7, k = i & 127;
        float s = g1[r] * rsqrtf(v1[r] + EPSV);
        int ht = r >> 4, r16 = r & 15, ks = k >> 5, g = (k >> 3) & 3, e = k & 7;
        w1f[((((ht * 4 + ks) * 4 + g) * 16 + r16) << 3) + e] = f2b(w1[i] * s);
    }
    // w2 fragment-linear: [ot 8][ch 12][ks 2][lane 64][e 8]
    for (int i = gid; i < OUP * HID; i += stp) {
        int r = i / HID, k = i - r * HID;
        float s = g3[r] * rsqrtf(v3[r] + EPSV);
        int ot = r >> 4, r16 = r & 15, ch = k >> 6, ks = (k >> 5) & 1, g = (k >> 3) & 3, e = k & 7;
        int lane = g * 16 + r16;
        w2f[((((ot * 12 + ch) * 2 + ks) * 64 + lane) << 3) + e] = f2b(w2[i] * s);
    }
    for (int i = gid; i < HID; i += stp) {
        float s1 = g1[i] * rsqrtf(v1[i] + EPSV);
        be1o[i] = b1[i] - m1[i] * s1;
        float s2 = g2[i] * rsqrtf(v2[i] + EPSV);
        be2o[i] = b2[i] - m2[i] * s2;
    }
    for (int i = gid; i < HID * 9; i += stp) {          // tap-major [q][c], BN2 scale folded
        int q = i / HID, c = i - q * HID;
        float s2 = g2[c] * rsqrtf(v2[c] + EPSV);
        wdsf[i] = wdw[c * 9 + q] * s2;
    }
    for (int i = gid; i < OUP; i += stp) {
        float s3 = g3[i] * rsqrtf(v3[i] + EPSV);
        be3o[i] = b3[i] - m3[i] * s3;
    }
    for (int i = gid; i < BATCH * HWSZ; i += stp) {     // mf + 3x3 dilated md
        int b = i / HWSZ, p = i - b * HWSZ;
        int y = p / WW, xx = p - y * WW;
        float mf = (float)mask[i];
        float md = 0.f;
        for (int dy = -1; dy <= 1; ++dy)
            for (int dx = -1; dx <= 1; ++dx) {
                int yy = y + dy, xc = xx + dx;
                if (yy >= 0 && yy < HH && xc >= 0 && xc < WW)
                    md = fmaxf(md, (float)mask[b * HWSZ + yy * WW + xc]);
            }
        mff[i] = mf;
        mdf[i] = md;
    }
}

// ---------------- K1: expand GEMM -> h1 (bf16 pair-interleaved [b][c/2][p]) — r10/r13 proven ----------------
__launch_bounds__(512, 4)
__global__ void k1_expand(const float* __restrict__ x,
                          const unsigned short* __restrict__ w1f,
                          const float* __restrict__ be1g,
                          const float* __restrict__ mdf,
                          unsigned* __restrict__ h1p)
{
    __shared__ unsigned short xs[128 * 128];   // 32 KB  bf16 x-tile [px][c] swizzled
    const int t = threadIdx.x, lane = t & 63, wv = t >> 6;
    const int g = lane >> 4, r16 = lane & 15;
    const int pid = blockIdx.x;
    const int l = (pid & 7) * 150 + (pid >> 3);
    const int hb = l % 3;
    const int pb = (l / 3) % 25;
    const int b  = l / 75;
    const int p0 = pb * 128;
    const int whid = wv & 3;
    const int wpx  = wv >> 2;

    for (int rep = 0; rep < 8; ++rep) {
        int id = t + rep * 512;
        int px = id & 127, c4 = id >> 7;
        int p = p0 + px;
        ushort4 u; u.x = 0; u.y = 0; u.z = 0; u.w = 0;
        if (p < HWSZ) {
            const float* xp = x + ((size_t)(b * INP + c4 * 4)) * HWSZ + p;
            unsigned lo = pkbf(xp[0], xp[HWSZ]);
            unsigned hi = pkbf(xp[2 * HWSZ], xp[3 * HWSZ]);
            u.x = (unsigned short)lo; u.y = (unsigned short)(lo >> 16);
            u.z = (unsigned short)hi; u.w = (unsigned short)(hi >> 16);
        }
        *(ushort4*)&xs[px * 128 + (((c4 >> 1) ^ (px & 15)) << 3) + ((c4 & 1) << 2)] = u;
    }
    __syncthreads();

    f32x4 acc[4][4];
    #pragma unroll
    for (int mt = 0; mt < 4; ++mt)
        #pragma unroll
        for (int nt = 0; nt < 4; ++nt) {
            acc[mt][nt][0] = 0.f; acc[mt][nt][1] = 0.f;
            acc[mt][nt][2] = 0.f; acc[mt][nt][3] = 0.f;
        }
    const int hbase = hb * 256 + whid * 64;
    const int htb = hbase >> 4;

    #pragma unroll
    for (int ks = 0; ks < 4; ++ks) {
        bf16x8 af[4];
        #pragma unroll
        for (int mt = 0; mt < 4; ++mt)
            af[mt] = *(const bf16x8*)&w1f[((((htb + mt) * 4 + ks) * 64) + lane) << 3];
        #pragma unroll
        for (int nt = 0; nt < 4; ++nt) {
            int px = wpx * 64 + nt * 16 + r16;
            bf16x8 bf = *(const bf16x8*)&xs[px * 128 + (((ks * 4 + g) ^ r16) << 3)];
            #pragma unroll
            for (int mt = 0; mt < 4; ++mt)
                acc[mt][nt] = __builtin_amdgcn_mfma_f32_16x16x32_bf16(af[mt], bf, acc[mt][nt], 0, 0, 0);
        }
    }

    #pragma unroll
    for (int nt = 0; nt < 4; ++nt) {
        const int pg = p0 + wpx * 64 + nt * 16;
        if (pg >= HWSZ) continue;
        const int p = pg + r16;
        const float md = mdf[b * HWSZ + p];
        #pragma unroll
        for (int mt = 0; mt < 4; ++mt) {
            const float4 be4 = *(const float4*)&be1g[hbase + mt * 16 + g * 4];
            f32x4 a = acc[mt][nt];
            float v0 = fminf(fmaxf(a[0] + be4.x, 0.f), 6.f) * md;
            float v1 = fminf(fmaxf(a[1] + be4.y, 0.f), 6.f) * md;
            float v2 = fminf(fmaxf(a[2] + be4.z, 0.f), 6.f) * md;
            float v3 = fminf(fmaxf(a[3] + be4.w, 0.f), 6.f) * md;
            const int c2 = (hbase >> 1) + mt * 8 + g * 2;
            const size_t ad = (size_t)(b * 384 + c2) * HWSZ + p;
            h1p[ad] = pkbf(v0, v1);
            h1p[ad + HWSZ] = pkbf(v2, v3);
        }
    }
}

// ---------------- K23: r13 structure + s_setprio around P MFMA cluster (T5) ----------------
__launch_bounds__(512, 4)
__global__ void k23(const unsigned* __restrict__ h1p,
                    const unsigned short* __restrict__ w2f,
                    const float* __restrict__ wdsf,
                    const float* __restrict__ be2g,
                    const float* __restrict__ be3g,
                    const float* __restrict__ mff,
                    const float* __restrict__ x,
                    float* __restrict__ out)
{
    __shared__ unsigned stg[4 * RWST];           // 31872 B  h1 rows [row 4][cp 32 x 62 dw]
    __shared__ unsigned short h2s[112 * H2STR];  // 16128 B  h2 [px][c] swizzled
    __shared__ float mfv_[112];                  //   448 B

    const int t = threadIdx.x, lane = t & 63, wv = t >> 6;
    const int g = lane >> 4, r16 = lane & 15;
    const int pid = blockIdx.x;
    const int l = (pid & 7) * 56 + (pid >> 3);   // XCD swizzle (448 = 8*56)
    const int strip = l % 28, b = l / 28;
    const int y0 = strip * 2, p0 = strip * 112;

    // ---------------- prologue ----------------
    if (t < 112) mfv_[t] = mff[b * HWSZ + p0 + t];
    if (t >= 128 && t < 384) {   // zero stg edge dwords (px=-1 at off 1, px=56 at off 58)
        int i = t - 128;
        int cp = i & 31, rs = (i >> 5) & 3, side = (i >> 7) & 1;
        stg[rs * RWST + cp * 62 + (side ? 58 : 1)] = 0;
    }

    // T14 stage state: 1792 tasks = cp32 x row4 x px4_14
    int gaddr[4], laddr[4]; bool gval[4], wval[4];
    #pragma unroll
    for (int rep = 0; rep < 4; ++rep) {
        const int id = t + rep * 512;
        const int rr  = (id * 4682) >> 16;            // id/14
        const int px4 = id - rr * 14;
        const int row = rr & 3, cp = rr >> 2;
        const int gy = y0 - 1 + row;
        wval[rep] = id < 1792;
        gval[rep] = wval[rep] && gy >= 0 && gy < HH;
        gaddr[rep] = (b * 384 + cp) * HWSZ + gy * WW + px4 * 4;
        laddr[rep] = row * RWST + cp * 62 + 2 + px4 * 4;
    }
    uint4 sreg[4];

    auto issueLoads = [&]() {
        #pragma unroll
        for (int rep = 0; rep < 4; ++rep) {
            uint4 u; u.x = 0; u.y = 0; u.z = 0; u.w = 0;
            if (gval[rep]) u = *(const uint4*)&h1p[gaddr[rep]];
            sreg[rep] = u;
            gaddr[rep] += 32 * HWSZ;                  // next chunk (+32 cp)
        }
    };
    auto stageWrite = [&]() {
        #pragma unroll
        for (int rep = 0; rep < 4; ++rep) {
            if (wval[rep]) {
                unsigned* s = &stg[laddr[rep]];
                uint2 a; a.x = sreg[rep].x; a.y = sreg[rep].y;
                uint2 c; c.x = sreg[rep].z; c.y = sreg[rep].w;
                *(uint2*)(s) = a;
                *(uint2*)(s + 2) = c;
            }
        }
    };

    // DW mapping: thread -> (cp 32, row2 2, q 8); 2 paired channels x 7 px each
    const int cp_c = t & 31, row2 = (t >> 5) & 1, q = t >> 6;   // q == wave id
    unsigned* const h2d = (unsigned*)h2s;

    auto phaseDW = [&](int ch) {
        const float2 be2 = *(const float2*)&be2g[ch * 64 + 2 * cp_c];
        float accL[7], accH[7];
        #pragma unroll
        for (int j = 0; j < 7; ++j) { accL[j] = be2.x; accH[j] = be2.y; }
        #pragma unroll
        for (int dy = 0; dy < 3; ++dy) {
            const float2 wt0 = *(const float2*)&wdsf[(dy * 3 + 0) * HID + ch * 64 + 2 * cp_c];
            const float2 wt1 = *(const float2*)&wdsf[(dy * 3 + 1) * HID + ch * 64 + 2 * cp_c];
            const float2 wt2 = *(const float2*)&wdsf[(dy * 3 + 2) * HID + ch * 64 + 2 * cp_c];
            const unsigned* rp = &stg[(row2 + dy) * RWST + cp_c * 62 + 1 + q * 7];
            float pL[9], pH[9];
            #pragma unroll
            for (int k = 0; k < 9; ++k) {
                unsigned u = rp[k];
                pL[k] = blo(u); pH[k] = bhi(u);
            }
            #pragma unroll
            for (int j = 0; j < 7; ++j) {
                accL[j] += pL[j] * wt0.x + pL[j + 1] * wt1.x + pL[j + 2] * wt2.x;
                accH[j] += pH[j] * wt0.y + pH[j + 1] * wt1.y + pH[j + 2] * wt2.y;
            }
        }
        #pragma unroll
        for (int j = 0; j < 7; ++j) {
            const int px = row2 * 56 + q * 7 + j;
            const float mv = mfv_[px];
            float vL = __builtin_amdgcn_fmed3f(accL[j], 0.f, 6.f) * mv;
            float vH = __builtin_amdgcn_fmed3f(accH[j], 0.f, 6.f) * mv;
            // full-dword write at P-read-compatible slot: octet (cp>>2)^(px&7), dword (cp&3)
            h2d[px * 36 + (((cp_c >> 2) ^ (px & 7)) << 2) + (cp_c & 3)] = pkbf(vL, vH);
        }
    };

    f32x4 pacc[7];
    #pragma unroll
    for (int nt = 0; nt < 7; ++nt) {
        pacc[nt][0] = 0.f; pacc[nt][1] = 0.f; pacc[nt][2] = 0.f; pacc[nt][3] = 0.f;
    }

    auto phaseP = [&](int ch) {
        __builtin_amdgcn_s_setprio(1);        // T5: favor MFMA-phase waves vs co-resident DW waves
        #pragma unroll
        for (int ks = 0; ks < 2; ++ks) {
            const bf16x8 pw = *(const bf16x8*)&w2f[((((wv * 12 + ch) * 2 + ks) * 64) + lane) << 3];
            #pragma unroll
            for (int nt = 0; nt < 7; ++nt) {
                const int px = nt * 16 + r16;
                const bf16x8 hb = *(const bf16x8*)&h2s[px * H2STR + (((ks * 4 + g) ^ (px & 7)) << 3)];
                pacc[nt] = __builtin_amdgcn_mfma_f32_16x16x32_bf16(pw, hb, pacc[nt], 0, 0, 0);
            }
        }
        __builtin_amdgcn_s_setprio(0);
    };

    // ---- main loop: loads for ch+1 fly under DW(ch); write lands under P(ch) ----
    issueLoads();
    stageWrite();
    __syncthreads();
    for (int ch = 0; ch < 12; ++ch) {
        if (ch + 1 < 12) issueLoads();
        phaseDW(ch);
        __syncthreads();                      // stg reads done; h2s written
        if (ch + 1 < 12) stageWrite();
        phaseP(ch);
        __syncthreads();                      // stg ready; h2s free
    }

    // ---- epilogue: out = x + (proj + be3) * mf ----
    {
        const int ob = wv * 16 + g * 4;
        const float4 be4 = *(const float4*)&be3g[ob];
        #pragma unroll
        for (int nt = 0; nt < 7; ++nt) {
            const int px = nt * 16 + r16;
            const float mv = mfv_[px];
            const size_t base = (size_t)(b * OUP + ob) * HWSZ + p0 + px;
            out[base]            = x[base]            + (pacc[nt][0] + be4.x) * mv;
            out[base + HWSZ]     = x[base + HWSZ]     + (pacc[nt][1] + be4.y) * mv;
            out[base + 2 * HWSZ] = x[base + 2 * HWSZ] + (pacc[nt][2] + be4.z) * mv;
            out[base + 3 * HWSZ] = x[base + 3 * HWSZ] + (pacc[nt][3] + be4.w) * mv;
        }
    }
}

extern "C" void kernel_launch(void* const* d_in, const int* in_sizes, int n_in,
                              void* d_out, int out_size, void* d_ws, size_t ws_size,
                              hipStream_t stream) {
    (void)in_sizes; (void)n_in; (void)out_size; (void)ws_size;
    const float* x   = (const float*)d_in[0];
    const float* w1  = (const float*)d_in[1];
    const float* g1  = (const float*)d_in[2];
    const float* b1  = (const float*)d_in[3];
    const float* m1  = (const float*)d_in[4];
    const float* v1  = (const float*)d_in[5];
    const float* wdw = (const float*)d_in[6];
    const float* g2  = (const float*)d_in[7];
    const float* b2  = (const float*)d_in[8];
    const float* m2  = (const float*)d_in[9];
    const float* v2  = (const float*)d_in[10];
    const float* w2  = (const float*)d_in[11];
    const float* g3  = (const float*)d_in[12];
    const float* b3  = (const float*)d_in[13];
    const float* m3  = (const float*)d_in[14];
    const float* v3  = (const float*)d_in[15];
    const int*  mask = (const int*)d_in[16];
    float* out = (float*)d_out;

    char* ws = (char*)d_ws;
    unsigned short* w1f = (unsigned short*)ws;                 // 196608 B
    unsigned short* w2f = (unsigned short*)(ws + 196608);      // 196608 B
    float* be1o = (float*)(ws + 393216);                       // 3072 B
    float* wdsf = (float*)(ws + 396288);                       // 27648 B  [9][768]
    float* be2o = (float*)(ws + 423936);                       // 3072 B
    float* be3o = (float*)(ws + 427008);                       // 512 B
    float* mdf  = (float*)(ws + 427520);                       // 200704 B
    float* mff  = (float*)(ws + 628224);                       // 200704 B
    unsigned* h1p = (unsigned*)(ws + 828928);                  // 77070336 B (bf16 pairs)

    prep<<<256, 256, 0, stream>>>(w1, g1, b1, m1, v1, wdw, g2, b2, m2, v2,
                                  w2, g3, b3, m3, v3, mask,
                                  w1f, w2f, be1o, wdsf, be2o, be3o, mdf, mff);
    k1_expand<<<dim3(1200), 512, 0, stream>>>(x, w1f, be1o, mdf, h1p);
    k23<<<dim3(448), 512, 0, stream>>>(h1p, w2f, wdsf, be2o, be3o, mff, x, out);
}